// Round 3
// baseline (260.531 us; speedup 1.0000x reference)
//
#include <hip/hip_runtime.h>
#include <math.h>

// mask[i][j] = (j < blk_end(i)) && (j != i),  blk_end = (i/n_nodes + 1)*n_nodes
// (equivalent to reference's ((i>j) | same_block) & (i!=j))
//
// Pure HBM-write-bound: n=8192 -> 268 MB fp32 out, ~0 bytes read.
// R7 == R6 resubmit (R6 hit an infra failure: container acquisition, kernel
// never ran). Structural clone of __amd_rocclr_fillBufferAligned (which
// sustains 6.6 TB/s on this exact path): 1D grid-stride loop, one plain
// float4 store per iteration, 2048 blocks x 256 threads -> 32 stores/thread
// back-to-back. NO nontemporal hint (R3/R4's regressions were nt-confounded:
// nt bypasses L2 write aggregation). Linear idx -> (i,j) via shifts.

__global__ void __launch_bounds__(256)
Create_Mask_23871428231714_kernel(const int* __restrict__ n_nodes_p,
                                  float* __restrict__ out, int n) {
    const int n_nodes = *n_nodes_p;                 // uniform s_load, L2 hit
    const int stride  = gridDim.x * blockDim.x;     // in float4 units
    int g = blockIdx.x * blockDim.x + threadIdx.x;  // float4 index

    float4* __restrict__ out4 = reinterpret_cast<float4*>(out);

    if (((n & (n - 1)) == 0) && ((n_nodes & (n_nodes - 1)) == 0)) {
        // fast path: both pow2 (the benched config: n=8192, n_nodes=64)
        const int sn = __ffs(n) - 1;
        const int sb = __ffs(n_nodes) - 1;
        const int total4 = (int)(((long long)n * (long long)n) >> 2);
        for (; g < total4; g += stride) {
            const int idx = g << 2;                 // linear element index
            const int i   = idx >> sn;              // row
            const int j0  = idx & (n - 1);          // col (n%4==0 -> same row)
            const int blk_end = ((i >> sb) + 1) << sb;
            float4 v;
            v.x = ((j0     < blk_end) && (j0     != i)) ? 1.0f : 0.0f;
            v.y = ((j0 + 1 < blk_end) && (j0 + 1 != i)) ? 1.0f : 0.0f;
            v.z = ((j0 + 2 < blk_end) && (j0 + 2 != i)) ? 1.0f : 0.0f;
            v.w = ((j0 + 3 < blk_end) && (j0 + 3 != i)) ? 1.0f : 0.0f;
            out4[g] = v;                            // coalesced 1 KB/wave
        }
    } else if ((n & 3) == 0) {
        // generic n_nodes / n, but n multiple of 4 (rows don't split a float4)
        const int total4 = (int)(((long long)n * (long long)n) >> 2);
        for (; g < total4; g += stride) {
            const int idx = g << 2;
            const int i   = idx / n;
            const int j0  = idx - i * n;
            const int blk_end = (i / n_nodes + 1) * n_nodes;
            float4 v;
            v.x = ((j0     < blk_end) && (j0     != i)) ? 1.0f : 0.0f;
            v.y = ((j0 + 1 < blk_end) && (j0 + 1 != i)) ? 1.0f : 0.0f;
            v.z = ((j0 + 2 < blk_end) && (j0 + 2 != i)) ? 1.0f : 0.0f;
            v.w = ((j0 + 3 < blk_end) && (j0 + 3 != i)) ? 1.0f : 0.0f;
            out4[g] = v;
        }
    } else {
        // fully generic scalar fallback
        const long long total = (long long)n * (long long)n;
        for (long long e = g; e < total; e += stride) {
            const int i = (int)(e / n);
            const int j = (int)(e - (long long)i * n);
            const int blk_end = (i / n_nodes + 1) * n_nodes;
            out[e] = ((j < blk_end) && (j != i)) ? 1.0f : 0.0f;
        }
    }
}

extern "C" void kernel_launch(void* const* d_in, const int* in_sizes, int n_in,
                              void* d_out, int out_size, void* d_ws, size_t ws_size,
                              hipStream_t stream) {
    (void)in_sizes; (void)n_in; (void)d_ws; (void)ws_size;
    const int* n_nodes_p = (const int*)d_in[0];
    float* out = (float*)d_out;

    // out is n x n -> recover n on host (no device readback; graph-capture safe)
    const int n = (int)llround(sqrt((double)out_size));

    // fillBuffer-like shape: modest grid, long per-thread store streams.
    // 2048 blocks = 8 blocks/CU; at n=8192 -> exactly 32 float4 stores/thread.
    const int block  = 256;
    const int blocks = 2048;
    Create_Mask_23871428231714_kernel<<<dim3(blocks, 1, 1), dim3(block, 1, 1),
                                        0, stream>>>(n_nodes_p, out, n);
}

// Round 4
// 247.935 us; speedup vs baseline: 1.0508x; 1.0508x over previous
//
#include <hip/hip_runtime.h>
#include <math.h>

// mask[i][j] = (j < blk_end(i)) && (j != i),  blk_end = (i/n_nodes + 1)*n_nodes
// (equivalent to reference's ((i>j) | same_block) & (i!=j))
//
// Pure HBM-write-bound: n=8192 -> 268 MB fp32 out, ~0 bytes read.
// R8 = revert to best-measured structure (R0: 248.4 us here, 248.7 us prior
// session). Session synthesis: timed region = harness re-poison fill
// (1.07 GB @ 6.65 TB/s ~ 161 us, fixed) + reset dispatches (~45 us, fixed)
// + this kernel (~40-50 us ~= 268 MB write floor). Three structural
// variants (one-shot max-split / 4x unroll / fillBuffer-clone grid-stride)
// all land within 5% total; one-shot max-split is best-measured. Kernel is
// at the write-BW floor; remaining time is harness-fixed.

__global__ void __launch_bounds__(256)
Create_Mask_23871428231714_kernel(const int* __restrict__ n_nodes_p,
                                  float* __restrict__ out, int n) {
    const int n_nodes = *n_nodes_p;                 // scalar, L2 broadcast
    const int i = blockIdx.y;                       // row
    const int j0 = (blockIdx.x * blockDim.x + threadIdx.x) << 2;

    // blk_end = (i/n_nodes + 1) * n_nodes; pow2 fast path (n_nodes=64)
    int blk_end;
    if ((n_nodes & (n_nodes - 1)) == 0) {
        const int s = __ffs(n_nodes) - 1;
        blk_end = ((i >> s) + 1) << s;
    } else {
        blk_end = (i / n_nodes + 1) * n_nodes;
    }

    float4 v;
    v.x = ((j0     < blk_end) && (j0     != i)) ? 1.0f : 0.0f;
    v.y = ((j0 + 1 < blk_end) && (j0 + 1 != i)) ? 1.0f : 0.0f;
    v.z = ((j0 + 2 < blk_end) && (j0 + 2 != i)) ? 1.0f : 0.0f;
    v.w = ((j0 + 3 < blk_end) && (j0 + 3 != i)) ? 1.0f : 0.0f;

    // n multiple of 4, j0 multiple of 4 -> 16B-aligned coalesced store
    *reinterpret_cast<float4*>(out + (size_t)i * (size_t)n + (size_t)j0) = v;
}

extern "C" void kernel_launch(void* const* d_in, const int* in_sizes, int n_in,
                              void* d_out, int out_size, void* d_ws, size_t ws_size,
                              hipStream_t stream) {
    (void)in_sizes; (void)n_in; (void)d_ws; (void)ws_size;
    const int* n_nodes_p = (const int*)d_in[0];
    float* out = (float*)d_out;

    // out is n x n -> recover n on host (no device readback; graph-capture safe)
    const int n = (int)llround(sqrt((double)out_size));

    const int block = 256;
    const int elems_per_block = block * 4;          // one float4 per thread
    dim3 grid((n + elems_per_block - 1) / elems_per_block, n, 1);
    Create_Mask_23871428231714_kernel<<<grid, dim3(block, 1, 1), 0, stream>>>(
        n_nodes_p, out, n);
}